// Round 3
// baseline (1136.799 us; speedup 1.0000x reference)
//
#include <hip/hip_runtime.h>
#include <hip/hip_bf16.h>

typedef __attribute__((ext_vector_type(4))) float floatx4;
typedef __attribute__((ext_vector_type(8))) __bf16 bf16x8;
typedef unsigned short ushort_t;

#define NENT  700
#define EMB   256
#define KDIM  1024
#define NDIM  512
#define HROWS 712   // 700 real + pad; ALL rows written

// ws byte offsets — total ~4.69 MB, all 16B-aligned
#define WS_HA   0
#define WS_HB   (WS_HA + HROWS*KDIM*2)
#define WS_W2T  (WS_HB + HROWS*KDIM*2)
#define WS_ENT  (WS_W2T + NDIM*KDIM*2)
#define WS_FLAG (WS_ENT + NENT*EMB*4)

// dtype-flagged scalar load: isbf ? bf16[i] : f32[i]
__device__ __forceinline__ float ldin(const void* p, int i, int isbf) {
    return isbf ? __bfloat162float(((const __hip_bfloat16*)p)[i])
                : ((const float*)p)[i];
}

// ---------------- stage 0: detect input dtype ----------------
// f32 N(0,0.05): even 16-bit words = low mantissa bits -> exp field uniform (~10% hit).
// bf16: even words = real elements -> exp field in [100,126] essentially always.
__global__ void detect_kernel(const ushort_t* __restrict__ w, int* __restrict__ flag) {
    if (threadIdx.x == 0) {
        int cnt = 0;
        for (int i = 0; i < 128; ++i) {
            int e = (w[2*i] >> 7) & 0xFF;
            if (e >= 100 && e <= 126) cnt++;
        }
        *flag = (cnt >= 96) ? 1 : 0;   // 1 = bf16 inputs, 0 = f32
    }
}

// ---------------- stage 1: ent = E @ W_ent (fp32), emit drug rows ----------------
__global__ void ent_kernel(const void* __restrict__ E, const void* __restrict__ Went,
                           const int* __restrict__ flag,
                           float* __restrict__ ent, void* __restrict__ out) {
    __shared__ float row[EMB];
    int i = blockIdx.x, t = threadIdx.x;
    int isbf = *flag;
    row[t] = ldin(E, i*EMB + t, isbf);
    __syncthreads();
    float s = 0.f;
#pragma unroll 8
    for (int k = 0; k < EMB; ++k)
        s += row[k] * ldin(Went, k*EMB + t, isbf);
    ent[i*EMB + t] = s;
    if (i < 200) {
        if (isbf) ((__hip_bfloat16*)out)[680000 + i*EMB + t] = __float2bfloat16(s);
        else      ((float*)out)[680000 + i*EMB + t] = s;
    }
}

// ---------------- stage 2: HA = ent@W1[:256] + b1 ; HB = ent@W1[256:] (bf16 out) ----------------
__global__ void hab_kernel(const float* __restrict__ ent,
                           const void* __restrict__ W1, const void* __restrict__ b1,
                           const int* __restrict__ flag,
                           __hip_bfloat16* __restrict__ HA, __hip_bfloat16* __restrict__ HB) {
    int part = blockIdx.y;           // 0 -> HA, 1 -> HB
    int ib = blockIdx.x * 8;
    int t = threadIdx.x;
    int isbf = *flag;
    __shared__ float rows[8][EMB];
#pragma unroll
    for (int r = 0; r < 8; ++r) {
        int i = ib + r;
        rows[r][t] = (i < NENT) ? ent[i*EMB + t] : 0.f;
    }
    __syncthreads();
    float acc[8][4];
#pragma unroll
    for (int r = 0; r < 8; ++r)
#pragma unroll
        for (int p = 0; p < 4; ++p) acc[r][p] = 0.f;

    int wbase = part*EMB*KDIM;
    for (int k = 0; k < EMB; ++k) {
        float w[4];
#pragma unroll
        for (int p = 0; p < 4; ++p)
            w[p] = ldin(W1, wbase + k*KDIM + t + p*256, isbf);
#pragma unroll
        for (int r = 0; r < 8; ++r) {
            float e = rows[r][k];
#pragma unroll
            for (int p = 0; p < 4; ++p) acc[r][p] += e * w[p];
        }
    }
    __hip_bfloat16* HX = part ? HB : HA;
#pragma unroll
    for (int r = 0; r < 8; ++r) {
#pragma unroll
        for (int p = 0; p < 4; ++p) {
            int n = t + p*256;
            float v = acc[r][p];
            if (!part) v += ldin(b1, n, isbf);
            HX[(ib + r)*KDIM + n] = __float2bfloat16(v);
        }
    }
}

// ---------------- prep: W2T[n][k] = bf16(W2[k][n]) ----------------
__global__ void prep_kernel(const void* __restrict__ W2, const int* __restrict__ flag,
                            __hip_bfloat16* __restrict__ W2T) {
    int idx = blockIdx.x*256 + threadIdx.x;
    int n = idx >> 10, k = idx & 1023;
    W2T[idx] = __float2bfloat16(ldin(W2, k*NDIM + n, *flag));
}

// ---------------- main: fused pair MLP (h gen -> MFMA GEMM -> W3 fold -> softmax) ----------------
__global__ __launch_bounds__(256, 2) void pair_kernel(
        const ushort_t* __restrict__ HA, const ushort_t* __restrict__ HB,
        const ushort_t* __restrict__ W2T,
        const void* __restrict__ b2, const void* __restrict__ W3, const void* __restrict__ b3,
        const int* __restrict__ flag, void* __restrict__ out) {

    const int blkEnd[10] = {650,1300,1800,2300,2800,3450,4100,4594,5088,5582};
    const int aB[10]  = {0,0,0,0,200,200,200,550,400,400};
    const int bB[10]  = {200,0,400,550,400,200,0,0,200,0};
    const int NaT[10] = {200,200,200,200,200,200,200,150,150,150};
    const int NbT[10] = {200,200,150,150,150,200,200,200,200,200};
    const int jTl[10] = {13,13,10,10,10,13,13,13,13,13};
    const int oOf[10] = {0,80000,160000,220000,280000,340000,420000,500000,560000,620000};

    int bid = blockIdx.x;
    int ty = 0;
    while (bid >= blkEnd[ty]) ty++;
    int lb = bid - (ty ? blkEnd[ty-1] : 0);
    int jT = jTl[ty];
    int it = lb / jT;
    int jt = lb - it*jT;
    int i0 = aB[ty] + it*4;    // 4 'a' rows per block
    int j0 = bB[ty] + jt*16;   // 16 'b' rows per block

    int tid  = threadIdx.x;
    int lane = tid & 63;
    int wn   = tid >> 6;       // wave id = n-quarter (128 n each)
    int l15  = lane & 15;
    int quad = lane >> 4;
    int isbf = *flag;

    const ushort_t* HAb  = HA  + i0*KDIM + quad*8;
    const ushort_t* HBb  = HB  + (j0 + l15)*KDIM + quad*8;   // rows <= 709 < HROWS, all written
    const ushort_t* W2Tb = W2T + (wn*128 + l15)*KDIM + quad*8;

    floatx4 acc[4][8];
#pragma unroll
    for (int f = 0; f < 4; ++f)
#pragma unroll
        for (int nf = 0; nf < 8; ++nf) acc[f][nf] = (floatx4){0.f,0.f,0.f,0.f};

#pragma unroll 2
    for (int kk = 0; kk < KDIM; kk += 32) {
        bf16x8 hbv = *(const bf16x8*)(HBb + kk);
        float hb[8];
#pragma unroll
        for (int j = 0; j < 8; ++j) hb[j] = (float)hbv[j];
        bf16x8 af[4];
#pragma unroll
        for (int f = 0; f < 4; ++f) {
            bf16x8 hav = *(const bf16x8*)(HAb + f*KDIM + kk);
            bf16x8 v;
#pragma unroll
            for (int j = 0; j < 8; ++j)
                v[j] = (__bf16)fmaxf((float)hav[j] + hb[j], 0.f);
            af[f] = v;
        }
#pragma unroll
        for (int nf = 0; nf < 8; ++nf) {
            bf16x8 bf_ = *(const bf16x8*)(W2Tb + nf*16*KDIM + kk);
#pragma unroll
            for (int f = 0; f < 4; ++f)
                acc[f][nf] = __builtin_amdgcn_mfma_f32_16x16x32_bf16(af[f], bf_, acc[f][nf], 0, 0, 0);
        }
    }

    // epilogue: h2 = relu(acc + b2); logits += h2 * W3; reduce over n
    __shared__ float lgt[4][64][2];
#pragma unroll
    for (int f = 0; f < 4; ++f) {
        float s0[4] = {0.f,0.f,0.f,0.f};
        float s1[4] = {0.f,0.f,0.f,0.f};
#pragma unroll
        for (int nf = 0; nf < 8; ++nf) {
            int n = wn*128 + nf*16 + l15;
            float b2v = ldin(b2, n, isbf);
            float wa  = ldin(W3, 2*n, isbf);
            float wb  = ldin(W3, 2*n+1, isbf);
            floatx4 c = acc[f][nf];
#pragma unroll
            for (int r = 0; r < 4; ++r) {
                float v = fmaxf(c[r] + b2v, 0.f);
                s0[r] += v * wa;
                s1[r] += v * wb;
            }
        }
#pragma unroll
        for (int off = 1; off < 16; off <<= 1) {
#pragma unroll
            for (int r = 0; r < 4; ++r) {
                s0[r] += __shfl_xor(s0[r], off, 64);
                s1[r] += __shfl_xor(s1[r], off, 64);
            }
        }
        if (l15 == 0) {
#pragma unroll
            for (int r = 0; r < 4; ++r) {
                int m = f*16 + quad*4 + r;
                lgt[wn][m][0] = s0[r];
                lgt[wn][m][1] = s1[r];
            }
        }
    }
    __syncthreads();

    if (tid < 64) {
        int m = tid;
        float l0 = lgt[0][m][0] + lgt[1][m][0] + lgt[2][m][0] + lgt[3][m][0] + ldin(b3, 0, isbf);
        float l1 = lgt[0][m][1] + lgt[1][m][1] + lgt[2][m][1] + lgt[3][m][1] + ldin(b3, 1, isbf);
        float mx = fmaxf(l0, l1);
        float e0 = __expf(l0 - mx), e1 = __expf(l1 - mx);
        float inv = 1.f / (e0 + e1);
        int il = m >> 4, jl = m & 15;
        int pi = it*4 + il, pj = jt*16 + jl;
        if (pi < NaT[ty] && pj < NbT[ty]) {
            int o = oOf[ty] + (pi*NbT[ty] + pj)*2;
            if (isbf) {
                __hip_bfloat16* ob = (__hip_bfloat16*)out;
                ob[o]   = __float2bfloat16(e0 * inv);
                ob[o+1] = __float2bfloat16(e1 * inv);
            } else {
                float* of = (float*)out;
                of[o]   = e0 * inv;
                of[o+1] = e1 * inv;
            }
        }
    }
}

extern "C" void kernel_launch(void* const* d_in, const int* in_sizes, int n_in,
                              void* d_out, int out_size, void* d_ws, size_t ws_size,
                              hipStream_t stream) {
    const void* E    = d_in[1];
    const void* Went = d_in[3];
    const void* W1   = d_in[5];
    const void* b1   = d_in[6];
    const void* W2   = d_in[7];
    const void* b2   = d_in[8];
    const void* W3   = d_in[9];
    const void* b3   = d_in[10];

    char* ws = (char*)d_ws;
    __hip_bfloat16* HA   = (__hip_bfloat16*)(ws + WS_HA);
    __hip_bfloat16* HB   = (__hip_bfloat16*)(ws + WS_HB);
    __hip_bfloat16* W2T  = (__hip_bfloat16*)(ws + WS_W2T);
    float*          entf = (float*)(ws + WS_ENT);
    int*            flag = (int*)(ws + WS_FLAG);

    detect_kernel<<<dim3(1), dim3(64), 0, stream>>>((const ushort_t*)E, flag);
    ent_kernel<<<dim3(700), dim3(256), 0, stream>>>(E, Went, flag, entf, d_out);
    hab_kernel<<<dim3(89, 2), dim3(256), 0, stream>>>(entf, W1, b1, flag, HA, HB);
    prep_kernel<<<dim3(2048), dim3(256), 0, stream>>>(W2, flag, W2T);
    pair_kernel<<<dim3(5582), dim3(256), 0, stream>>>((const ushort_t*)HA, (const ushort_t*)HB,
                                                      (const ushort_t*)W2T, b2, W3, b3, flag, d_out);
}

// Round 4
// 854.194 us; speedup vs baseline: 1.3308x; 1.3308x over previous
//
#include <hip/hip_runtime.h>
#include <hip/hip_bf16.h>

typedef __attribute__((ext_vector_type(4))) float floatx4;
typedef __attribute__((ext_vector_type(8))) __bf16 bf16x8;
typedef unsigned short ushort_t;

#define NENT  700
#define EMB   256
#define KDIM  1024
#define NDIM  512
#define HROWS 712   // 89*8: every row written by hab_kernel
#define HPAD  1032  // LDS row stride (elems): 1024 + 8 pad -> conflict-free ds_read_b128

// ws byte offsets — total ~4.69 MB
#define WS_HA   0
#define WS_HB   (WS_HA + HROWS*KDIM*2)
#define WS_W2T  (WS_HB + HROWS*KDIM*2)
#define WS_ENT  (WS_W2T + NDIM*KDIM*2)
#define WS_FLAG (WS_ENT + NENT*EMB*4)

__device__ __forceinline__ float ldin(const void* p, int i, int isbf) {
    return isbf ? __bfloat162float(((const __hip_bfloat16*)p)[i])
                : ((const float*)p)[i];
}

// ---------------- stage 0: detect input dtype (f32 vs bf16) ----------------
__global__ void detect_kernel(const ushort_t* __restrict__ w, int* __restrict__ flag) {
    if (threadIdx.x == 0) {
        int cnt = 0;
        for (int i = 0; i < 128; ++i) {
            int e = (w[2*i] >> 7) & 0xFF;
            if (e >= 100 && e <= 126) cnt++;
        }
        *flag = (cnt >= 96) ? 1 : 0;   // 1 = bf16 inputs, 0 = f32
    }
}

// ---------------- stage 1: ent = E @ W_ent, 8 rows/block (Went read 88x not 700x) ----------------
__global__ void ent_kernel(const void* __restrict__ E, const void* __restrict__ Went,
                           const int* __restrict__ flag,
                           float* __restrict__ ent, void* __restrict__ out) {
    int ib = blockIdx.x * 8, t = threadIdx.x;
    int isbf = *flag;
    __shared__ float rows[8][EMB];
#pragma unroll
    for (int r = 0; r < 8; ++r) {
        int i = ib + r;
        rows[r][t] = (i < NENT) ? ldin(E, i*EMB + t, isbf) : 0.f;
    }
    __syncthreads();
    float acc[8] = {0.f,0.f,0.f,0.f,0.f,0.f,0.f,0.f};
    if (isbf) {
        const __hip_bfloat16* W = (const __hip_bfloat16*)Went;
        for (int k = 0; k < EMB; ++k) {
            float w = __bfloat162float(W[k*EMB + t]);
#pragma unroll
            for (int r = 0; r < 8; ++r) acc[r] += rows[r][k] * w;
        }
    } else {
        const float* W = (const float*)Went;
        for (int k = 0; k < EMB; ++k) {
            float w = W[k*EMB + t];
#pragma unroll
            for (int r = 0; r < 8; ++r) acc[r] += rows[r][k] * w;
        }
    }
#pragma unroll
    for (int r = 0; r < 8; ++r) {
        int i = ib + r;
        if (i < NENT) {
            ent[i*EMB + t] = acc[r];
            if (i < 200) {
                if (isbf) ((__hip_bfloat16*)out)[680000 + i*EMB + t] = __float2bfloat16(acc[r]);
                else      ((float*)out)[680000 + i*EMB + t] = acc[r];
            }
        }
    }
}

// ---------------- stage 2: HA = ent@W1[:256] + b1 ; HB = ent@W1[256:] (bf16 out) ----------------
__global__ void hab_kernel(const float* __restrict__ ent,
                           const void* __restrict__ W1, const void* __restrict__ b1,
                           const int* __restrict__ flag,
                           __hip_bfloat16* __restrict__ HA, __hip_bfloat16* __restrict__ HB) {
    int part = blockIdx.y;           // 0 -> HA, 1 -> HB
    int ib = blockIdx.x * 8;
    int t = threadIdx.x;
    int isbf = *flag;
    __shared__ float rows[8][EMB];
#pragma unroll
    for (int r = 0; r < 8; ++r) {
        int i = ib + r;
        rows[r][t] = (i < NENT) ? ent[i*EMB + t] : 0.f;
    }
    __syncthreads();
    float acc[8][4];
#pragma unroll
    for (int r = 0; r < 8; ++r)
#pragma unroll
        for (int p = 0; p < 4; ++p) acc[r][p] = 0.f;

    int wbase = part*EMB*KDIM;
    if (isbf) {
        const __hip_bfloat16* W = (const __hip_bfloat16*)W1;
        for (int k = 0; k < EMB; ++k) {
            float w[4];
#pragma unroll
            for (int p = 0; p < 4; ++p) w[p] = __bfloat162float(W[wbase + k*KDIM + t + p*256]);
#pragma unroll
            for (int r = 0; r < 8; ++r) {
                float e = rows[r][k];
#pragma unroll
                for (int p = 0; p < 4; ++p) acc[r][p] += e * w[p];
            }
        }
    } else {
        const float* W = (const float*)W1;
        for (int k = 0; k < EMB; ++k) {
            float w[4];
#pragma unroll
            for (int p = 0; p < 4; ++p) w[p] = W[wbase + k*KDIM + t + p*256];
#pragma unroll
            for (int r = 0; r < 8; ++r) {
                float e = rows[r][k];
#pragma unroll
                for (int p = 0; p < 4; ++p) acc[r][p] += e * w[p];
            }
        }
    }
    __hip_bfloat16* HX = part ? HB : HA;
#pragma unroll
    for (int r = 0; r < 8; ++r) {
#pragma unroll
        for (int p = 0; p < 4; ++p) {
            int n = t + p*256;
            float v = acc[r][p];
            if (!part) v += ldin(b1, n, isbf);
            HX[(ib + r)*KDIM + n] = __float2bfloat16(v);
        }
    }
}

// ---------------- prep: W2T[n][k] = bf16(W2[k][n]) ----------------
__global__ void prep_kernel(const void* __restrict__ W2, const int* __restrict__ flag,
                            __hip_bfloat16* __restrict__ W2T) {
    int idx = blockIdx.x*256 + threadIdx.x;
    int n = idx >> 10, k = idx & 1023;
    W2T[idx] = __float2bfloat16(ldin(W2, k*NDIM + n, *flag));
}

// round-half-up f32->bf16 pair pack (post-relu values are non-negative; ties-only diff vs RNE)
union U8 { bf16x8 v; unsigned u[4]; };

// ---------------- main: fused pair MLP ----------------
__global__ __launch_bounds__(256, 2) void pair_kernel(
        const ushort_t* __restrict__ HA, const ushort_t* __restrict__ HB,
        const ushort_t* __restrict__ W2T,
        const void* __restrict__ b2, const void* __restrict__ W3, const void* __restrict__ b3,
        const int* __restrict__ flag, void* __restrict__ out) {

    const int blkEnd[10] = {650,1300,1800,2300,2800,3450,4100,4594,5088,5582};
    const int aB[10]  = {0,0,0,0,200,200,200,550,400,400};
    const int bB[10]  = {200,0,400,550,400,200,0,0,200,0};
    const int NaT[10] = {200,200,200,200,200,200,200,150,150,150};
    const int NbT[10] = {200,200,150,150,150,200,200,200,200,200};
    const int jTl[10] = {13,13,10,10,10,13,13,13,13,13};
    const int oOf[10] = {0,80000,160000,220000,280000,340000,420000,500000,560000,620000};

    __shared__ ushort_t sHB[16*HPAD];   // 33,024 B
    __shared__ ushort_t sHA[4*HPAD];    //  8,256 B
    __shared__ float lgt[4][64][2];     //  2,048 B

    int bid = blockIdx.x;
    int ty = 0;
    while (bid >= blkEnd[ty]) ty++;
    int lb = bid - (ty ? blkEnd[ty-1] : 0);
    int jT = jTl[ty];
    int it = lb / jT;
    int jt = lb - it*jT;
    int i0 = aB[ty] + it*4;    // 4 'a' rows per block
    int j0 = bB[ty] + jt*16;   // 16 'b' rows per block

    int tid  = threadIdx.x;
    int lane = tid & 63;
    int wn   = tid >> 6;       // wave id = n-quarter (128 n each)
    int l15  = lane & 15;
    int quad = lane >> 4;
    int isbf = *flag;

    // ---- stage HB (16 rows) and HA (4 rows) into LDS, padded rows ----
#pragma unroll
    for (int ii = 0; ii < 8; ++ii) {           // 2048 frags of 8 elems
        int idx = tid + ii*256;
        int r = idx >> 7, c = (idx & 127) << 3;
        *(bf16x8*)(sHB + r*HPAD + c) = *(const bf16x8*)(HB + (j0 + r)*KDIM + c);
    }
#pragma unroll
    for (int ii = 0; ii < 2; ++ii) {           // 512 frags
        int idx = tid + ii*256;
        int r = idx >> 7, c = (idx & 127) << 3;
        *(bf16x8*)(sHA + r*HPAD + c) = *(const bf16x8*)(HA + (i0 + r)*KDIM + c);
    }
    __syncthreads();

    const ushort_t* W2Tb = W2T + (wn*128 + l15)*KDIM + quad*8;
    const ushort_t* sHBp = sHB + l15*HPAD + quad*8;
    const ushort_t* sHAp = sHA + quad*8;

    floatx4 acc[4][8];
#pragma unroll
    for (int f = 0; f < 4; ++f)
#pragma unroll
        for (int nf = 0; nf < 8; ++nf) acc[f][nf] = (floatx4){0.f,0.f,0.f,0.f};

    // prime register double-buffer with k-step 0 of W2T
    bf16x8 curB[8];
#pragma unroll
    for (int nf = 0; nf < 8; ++nf)
        curB[nf] = *(const bf16x8*)(W2Tb + nf*16*KDIM);

#pragma unroll 2
    for (int kk = 0; kk < KDIM; kk += 32) {
        // prefetch next k-step's B fragments (wraps to 0 on last iter — harmless)
        int kn = (kk + 32) & (KDIM - 1);
        bf16x8 nxtB[8];
#pragma unroll
        for (int nf = 0; nf < 8; ++nf)
            nxtB[nf] = *(const bf16x8*)(W2Tb + nf*16*KDIM + kn);

        // A-fragment generation from LDS
        bf16x8 hbv = *(const bf16x8*)(sHBp + kk);
        float hb[8];
#pragma unroll
        for (int j = 0; j < 8; ++j) hb[j] = (float)hbv[j];
        bf16x8 af[4];
#pragma unroll
        for (int f = 0; f < 4; ++f) {
            bf16x8 hav = *(const bf16x8*)(sHAp + f*HPAD + kk);
            U8 r;
#pragma unroll
            for (int j = 0; j < 4; ++j) {
                float x0 = fmaxf((float)hav[2*j]   + hb[2*j],   0.f);
                float x1 = fmaxf((float)hav[2*j+1] + hb[2*j+1], 0.f);
                unsigned u0 = __float_as_uint(x0) + 0x8000u;
                unsigned u1 = __float_as_uint(x1) + 0x8000u;
                r.u[j] = (u0 >> 16) | (u1 & 0xFFFF0000u);
            }
            af[f] = r.v;
        }
#pragma unroll
        for (int nf = 0; nf < 8; ++nf) {
#pragma unroll
            for (int f = 0; f < 4; ++f)
                acc[f][nf] = __builtin_amdgcn_mfma_f32_16x16x32_bf16(af[f], curB[nf], acc[f][nf], 0, 0, 0);
        }
#pragma unroll
        for (int nf = 0; nf < 8; ++nf) curB[nf] = nxtB[nf];
    }

    // epilogue: h2 = relu(acc + b2); logits += h2 * W3; reduce over n
#pragma unroll
    for (int f = 0; f < 4; ++f) {
        float s0[4] = {0.f,0.f,0.f,0.f};
        float s1[4] = {0.f,0.f,0.f,0.f};
#pragma unroll
        for (int nf = 0; nf < 8; ++nf) {
            int n = wn*128 + nf*16 + l15;
            float b2v = ldin(b2, n, isbf);
            float wa  = ldin(W3, 2*n, isbf);
            float wb  = ldin(W3, 2*n+1, isbf);
            floatx4 c = acc[f][nf];
#pragma unroll
            for (int r = 0; r < 4; ++r) {
                float v = fmaxf(c[r] + b2v, 0.f);
                s0[r] += v * wa;
                s1[r] += v * wb;
            }
        }
#pragma unroll
        for (int off = 1; off < 16; off <<= 1) {
#pragma unroll
            for (int r = 0; r < 4; ++r) {
                s0[r] += __shfl_xor(s0[r], off, 64);
                s1[r] += __shfl_xor(s1[r], off, 64);
            }
        }
        if (l15 == 0) {
#pragma unroll
            for (int r = 0; r < 4; ++r) {
                int m = f*16 + quad*4 + r;
                lgt[wn][m][0] = s0[r];
                lgt[wn][m][1] = s1[r];
            }
        }
    }
    __syncthreads();

    if (tid < 64) {
        int m = tid;
        float l0 = lgt[0][m][0] + lgt[1][m][0] + lgt[2][m][0] + lgt[3][m][0] + ldin(b3, 0, isbf);
        float l1 = lgt[0][m][1] + lgt[1][m][1] + lgt[2][m][1] + lgt[3][m][1] + ldin(b3, 1, isbf);
        float mx = fmaxf(l0, l1);
        float e0 = __expf(l0 - mx), e1 = __expf(l1 - mx);
        float inv = 1.f / (e0 + e1);
        int il = m >> 4, jl = m & 15;
        int pi = it*4 + il, pj = jt*16 + jl;
        if (pi < NaT[ty] && pj < NbT[ty]) {
            int o = oOf[ty] + (pi*NbT[ty] + pj)*2;
            if (isbf) {
                __hip_bfloat16* ob = (__hip_bfloat16*)out;
                ob[o]   = __float2bfloat16(e0 * inv);
                ob[o+1] = __float2bfloat16(e1 * inv);
            } else {
                float* of = (float*)out;
                of[o]   = e0 * inv;
                of[o+1] = e1 * inv;
            }
        }
    }
}

extern "C" void kernel_launch(void* const* d_in, const int* in_sizes, int n_in,
                              void* d_out, int out_size, void* d_ws, size_t ws_size,
                              hipStream_t stream) {
    const void* E    = d_in[1];
    const void* Went = d_in[3];
    const void* W1   = d_in[5];
    const void* b1   = d_in[6];
    const void* W2   = d_in[7];
    const void* b2   = d_in[8];
    const void* W3   = d_in[9];
    const void* b3   = d_in[10];

    char* ws = (char*)d_ws;
    __hip_bfloat16* HA   = (__hip_bfloat16*)(ws + WS_HA);
    __hip_bfloat16* HB   = (__hip_bfloat16*)(ws + WS_HB);
    __hip_bfloat16* W2T  = (__hip_bfloat16*)(ws + WS_W2T);
    float*          entf = (float*)(ws + WS_ENT);
    int*            flag = (int*)(ws + WS_FLAG);

    detect_kernel<<<dim3(1), dim3(64), 0, stream>>>((const ushort_t*)E, flag);
    ent_kernel<<<dim3(88), dim3(256), 0, stream>>>(E, Went, flag, entf, d_out);
    hab_kernel<<<dim3(89, 2), dim3(256), 0, stream>>>(entf, W1, b1, flag, HA, HB);
    prep_kernel<<<dim3(2048), dim3(256), 0, stream>>>(W2, flag, W2T);
    pair_kernel<<<dim3(5582), dim3(256), 0, stream>>>((const ushort_t*)HA, (const ushort_t*)HB,
                                                      (const ushort_t*)W2T, b2, W3, b3, flag, d_out);
}